// Round 5
// baseline (209.803 us; speedup 1.0000x reference)
//
#include <hip/hip_runtime.h>

#define NUM_SEG 32
#define MUL 128
#define D 3
#define NUM_PATHS 64
#define ROW (NUM_SEG * MUL * D)   // 12288 floats per batch row
#define SEGF (MUL * D)            // 384 floats per full segment row
#define SEG_HF 192                // floats per segment in a u-half (64 u * 3)
#define NBLK 512                  // persistent-ish grid: 2 blocks/CU
#define M_STRIDE 16               // m row padded 9 -> 16 floats (uniform DMA)

typedef float v2f __attribute__((ext_vector_type(2)));
typedef float v4f __attribute__((ext_vector_type(4)));

// ---------------------------------------------------------------------------
// Setup kernel: block 0 builds the compact schedule (segments sorted by
// path-count desc); blocks 1..B build m[b][p][16] (9 used, stride 16).
// ---------------------------------------------------------------------------
__global__ __launch_bounds__(64) void ftp_setup(
    const float* __restrict__ x1, const float* __restrict__ coeff,
    const int* __restrict__ idx0, const int* __restrict__ idx1,
    const int* __restrict__ idx2,
    unsigned int* __restrict__ sched, float* __restrict__ m)
{
    const int tid = threadIdx.x;
    if (blockIdx.x == 0) {
        __shared__ int lcnt[NUM_SEG];
        __shared__ int loff[NUM_SEG];
        __shared__ int lperm[NUM_SEG];
        __shared__ unsigned short lent[NUM_PATHS];
        if (tid < NUM_SEG) lcnt[tid] = 0;
        __syncthreads();
        const int p   = tid;
        const int s2  = idx2[p];
        const int pos = atomicAdd(&lcnt[s2], 1);
        __syncthreads();
        if (tid == 0) {
            int off = 0;
            for (int s = 0; s < NUM_SEG; ++s) { loff[s] = off; off += lcnt[s]; }
            int perm[NUM_SEG];
            for (int s = 0; s < NUM_SEG; ++s) perm[s] = s;
            for (int i = 1; i < NUM_SEG; ++i) {          // insertion sort, cnt desc
                int v = perm[i], cv = lcnt[v], j = i - 1;
                while (j >= 0 && lcnt[perm[j]] < cv) { perm[j + 1] = perm[j]; --j; }
                perm[j + 1] = v;
            }
            for (int s = 0; s < NUM_SEG; ++s) lperm[s] = perm[s];
        }
        __syncthreads();
        lent[loff[s2] + pos] = (unsigned short)(idx0[p] | (p << 8));
        __syncthreads();
        if (tid < NUM_SEG) {
            const int sg = lperm[tid];
            sched[tid] = (unsigned)lcnt[sg] | ((unsigned)loff[sg] << 8)
                       | ((unsigned)sg << 16);
        }
        if (tid < NUM_PATHS / 2) {
            sched[NUM_SEG + tid] = (unsigned)lent[2 * tid]
                                 | ((unsigned)lent[2 * tid + 1] << 16);
        }
    } else {
        const int b = blockIdx.x - 1;
        const int p = tid;
        const float* xr = x1 + (size_t)b * (NUM_SEG * D) + idx1[p] * D;
        const float j0 = xr[0], j1 = xr[1], j2 = xr[2];
        const float* cf = coeff + p * 27;
        float* mp = m + (size_t)b * (NUM_PATHS * M_STRIDE) + p * M_STRIDE;
        #pragma unroll
        for (int i = 0; i < D; ++i)
            #pragma unroll
            for (int k = 0; k < D; ++k)
                mp[i * 3 + k] = j0 * cf[i * 9 + k]
                              + j1 * cf[i * 9 + 3 + k]
                              + j2 * cf[i * 9 + 6 + k];
    }
}

// ---------------------------------------------------------------------------
// Tile stage: 6 x gl_lds16 (x0 u-half) + 4 x gl_lds4 (m) = 10 vmem instr
// per wave, uniform -> exact counted vmcnt.
// ---------------------------------------------------------------------------
__device__ __forceinline__ void stage_tile(
    const float* __restrict__ x0, const float* __restrict__ m,
    int t, float* s_x0buf, float* s_mbuf, int tid)
{
    const int b = t >> 1, h = t & 1;
    const v4f* src = (const v4f*)(x0 + (size_t)b * ROW);
    #pragma unroll
    for (int j = 0; j < 6; ++j) {
        const int F   = j * 256 + tid;       // f4 index in [0,1536)
        const int seg = F / 48;
        const int in4 = F - seg * 48;
        __builtin_amdgcn_global_load_lds(
            (const __attribute__((address_space(1))) void*)(src + seg * 96 + h * 48 + in4),
            (__attribute__((address_space(3))) void*)((v4f*)s_x0buf + F),
            16, 0, 0);
    }
    const float* msrc = m + (size_t)b * (NUM_PATHS * M_STRIDE);
    #pragma unroll
    for (int j = 0; j < 4; ++j) {
        const int F = j * 256 + tid;
        __builtin_amdgcn_global_load_lds(
            (const __attribute__((address_space(1))) void*)(msrc + F),
            (__attribute__((address_space(3))) void*)(s_mbuf + F),
            4, 0, 0);
    }
}

// ---------------------------------------------------------------------------
// Main kernel: persistent 2-phase pipeline. Stage tile k+1 BEFORE computing
// tile k; counted s_waitcnt vmcnt(10) (never 0 mid-loop); raw s_barrier so
// the compiler can't insert a vmcnt(0) drain. 57.9 KB LDS -> 2 blocks/CU.
// ---------------------------------------------------------------------------
__global__ __launch_bounds__(256) void ftp_main(
    const float* __restrict__ x0, const unsigned int* __restrict__ sched,
    const float* __restrict__ m, float* __restrict__ out, int B)
{
    __shared__ __align__(16) float s_x0[2][NUM_SEG * SEG_HF];   // 2 x 24576 B
    __shared__ __align__(16) float s_m[2][NUM_PATHS * M_STRIDE];// 2 x 4096 B
    __shared__ unsigned int s_sched[NUM_SEG];                   //   128 B
    __shared__ unsigned int s_entw[NUM_PATHS / 2];              //   128 B

    const int tid = threadIdx.x;
    if (tid < 32)      s_sched[tid]      = sched[tid];
    else if (tid < 64) s_entw[tid - 32]  = sched[tid];

    const int nt = B * 2;
    int t = blockIdx.x;
    if (t >= nt) return;

    stage_tile(x0, m, t, s_x0[0], s_m[0], tid);
    asm volatile("s_waitcnt lgkmcnt(0)" ::: "memory");   // sched writes visible

    const int g = tid >> 5;            // half-wave group 0..7 (one seg slot each)
    const int q = tid & 31;            // u-pair: local u = 2q, 2q+1
    const unsigned short* s_ent = (const unsigned short*)s_entw;
    int cur = 0;

    while (t < nt) {
        const int tn = t + NBLK;
        if (tn < nt) {
            stage_tile(x0, m, tn, s_x0[cur ^ 1], s_m[cur ^ 1], tid);
            asm volatile("s_waitcnt vmcnt(10)" ::: "memory"); // tile t landed; t+1 in flight
        } else {
            asm volatile("s_waitcnt vmcnt(0)" ::: "memory");
        }
        __builtin_amdgcn_s_barrier();

        const float* sx = s_x0[cur];
        const float* sm = s_m[cur];
        const int b = t >> 1, h = t & 1;
        float* __restrict__ ob = out + (size_t)b * ROW + h * SEG_HF + q * 6;

        #pragma unroll
        for (int r = 0; r < 4; ++r) {
            // snake over count-sorted ranks: g, 15-g, 16+g, 31-g -> uniform sums
            const int rank = (r == 0) ? g : (r == 1) ? (15 - g)
                           : (r == 2) ? (16 + g) : (31 - g);
            const unsigned sc = s_sched[rank];
            const int n   = sc & 255;
            const int off = (sc >> 8) & 255;
            const int s   = sc >> 16;
            float a00 = 0, a01 = 0, a02 = 0, a10 = 0, a11 = 0, a12 = 0;
            for (int ei = 0; ei < n; ++ei) {
                const int e = s_ent[off + ei];       // seg0 | p<<8 (32-lane uniform)
                const float* xs = sx + (e & 255) * SEG_HF + q * 6;
                const float u00 = xs[0], u01 = xs[1], u02 = xs[2];
                const float u10 = xs[3], u11 = xs[4], u12 = xs[5];
                const float* mm = sm + (e >> 8) * M_STRIDE;   // broadcast
                a00 += u00 * mm[0] + u01 * mm[3] + u02 * mm[6];
                a01 += u00 * mm[1] + u01 * mm[4] + u02 * mm[7];
                a02 += u00 * mm[2] + u01 * mm[5] + u02 * mm[8];
                a10 += u10 * mm[0] + u11 * mm[3] + u12 * mm[6];
                a11 += u10 * mm[1] + u11 * mm[4] + u12 * mm[7];
                a12 += u10 * mm[2] + u11 * mm[5] + u12 * mm[8];
            }
            float* o = ob + s * SEGF;   // 32 lanes * 8B consecutive: full 64B lines
            v2f O0 = {a00, a01}, O1 = {a02, a10}, O2 = {a11, a12};
            *(v2f*)(o + 0) = O0;
            *(v2f*)(o + 2) = O1;
            *(v2f*)(o + 4) = O2;
        }
        __builtin_amdgcn_s_barrier();   // buf[cur] free before next stage overwrites
        t = tn; cur ^= 1;
    }
}

// ---------------------------------------------------------------------------
// Fallback: original verified kernel (used only if ws_size is too small).
// ---------------------------------------------------------------------------
#define HALF_F4 1536

__global__ __launch_bounds__(256) void ftp_kernel(
    const float* __restrict__ x0, const float* __restrict__ x1,
    const float* __restrict__ coeff, const int* __restrict__ idx0,
    const int* __restrict__ idx1, const int* __restrict__ idx2,
    float* __restrict__ out)
{
    const int bid = blockIdx.x;
    const int b   = bid >> 1;
    const int h   = bid & 1;
    const int tid = threadIdx.x;

    __shared__ v4f   s_x0[HALF_F4];
    __shared__ float s_m[NUM_PATHS][9];
    __shared__ unsigned short s_pe[NUM_SEG][NUM_PATHS];
    __shared__ int   s_cnt[NUM_SEG];

    if (tid < NUM_SEG) s_cnt[tid] = 0;
    __syncthreads();

    const v4f* __restrict__ src = (const v4f*)(x0 + (size_t)b * ROW);
    #pragma unroll
    for (int j = 0; j < 6; ++j) {
        const int f     = j * 256 + tid;
        const int seg   = f / 48;
        const int inner = f - seg * 48;
        s_x0[f] = src[seg * 96 + h * 48 + inner];
    }

    if (tid < NUM_PATHS) {
        const int p  = tid;
        const int s0 = idx0[p];
        const int i1 = idx1[p];
        const int s2 = idx2[p];
        const int pos = atomicAdd(&s_cnt[s2], 1);
        s_pe[s2][pos] = (unsigned short)(s0 | (p << 8));

        const float* xr = x1 + (size_t)b * (NUM_SEG * D) + i1 * D;
        const float j0 = xr[0], j1 = xr[1], j2 = xr[2];
        const float* cf = coeff + p * 27;
        #pragma unroll
        for (int i = 0; i < D; ++i)
            #pragma unroll
            for (int k = 0; k < D; ++k)
                s_m[p][i * 3 + k] = j0 * cf[i * 9 + k]
                                  + j1 * cf[i * 9 + 3 + k]
                                  + j2 * cf[i * 9 + 6 + k];
    }
    __syncthreads();

    const int q  = tid & 31;
    const int ss = tid >> 5;
    float* __restrict__ ob = out + (size_t)b * ROW + h * SEG_HF + q * 6;
    const float* __restrict__ sx = (const float*)s_x0;

    #pragma unroll
    for (int si = 0; si < 4; ++si) {
        const int s = ss + si * 8;
        float a00 = 0, a01 = 0, a02 = 0, a10 = 0, a11 = 0, a12 = 0;
        const int n = s_cnt[s];
        for (int t = 0; t < n; ++t) {
            const int e = s_pe[s][t];
            const float* xs = sx + (e & 255) * SEG_HF + q * 6;
            const float u00 = xs[0], u01 = xs[1], u02 = xs[2];
            const float u10 = xs[3], u11 = xs[4], u12 = xs[5];
            const float* mm = s_m[e >> 8];
            a00 += u00 * mm[0] + u01 * mm[3] + u02 * mm[6];
            a01 += u00 * mm[1] + u01 * mm[4] + u02 * mm[7];
            a02 += u00 * mm[2] + u01 * mm[5] + u02 * mm[8];
            a10 += u10 * mm[0] + u11 * mm[3] + u12 * mm[6];
            a11 += u10 * mm[1] + u11 * mm[4] + u12 * mm[7];
            a12 += u10 * mm[2] + u11 * mm[5] + u12 * mm[8];
        }
        float* o = ob + s * SEGF;
        v2f O0 = {a00, a01}, O1 = {a02, a10}, O2 = {a11, a12};
        *(v2f*)(o + 0) = O0;
        *(v2f*)(o + 2) = O1;
        *(v2f*)(o + 4) = O2;
    }
}

extern "C" void kernel_launch(void* const* d_in, const int* in_sizes, int n_in,
                              void* d_out, int out_size, void* d_ws, size_t ws_size,
                              hipStream_t stream) {
    const float* x0    = (const float*)d_in[0];
    const float* x1    = (const float*)d_in[1];
    const float* coeff = (const float*)d_in[2];
    const int*   idx0  = (const int*)d_in[3];
    const int*   idx1  = (const int*)d_in[4];
    const int*   idx2  = (const int*)d_in[5];
    float* out = (float*)d_out;

    const int B = in_sizes[0] / ROW;

    const size_t schedBytes = (size_t)(NUM_SEG + NUM_PATHS / 2) * sizeof(unsigned int);
    const size_t schedPad   = (schedBytes + 255) & ~(size_t)255;   // 256B-align m
    const size_t mBytes     = (size_t)B * NUM_PATHS * M_STRIDE * sizeof(float);

    if (ws_size >= schedPad + mBytes) {
        unsigned int* sched = (unsigned int*)d_ws;
        float*        m     = (float*)((char*)d_ws + schedPad);
        ftp_setup<<<B + 1, 64, 0, stream>>>(x1, coeff, idx0, idx1, idx2, sched, m);
        const int grid = (B * 2 < NBLK) ? B * 2 : NBLK;
        ftp_main<<<grid, 256, 0, stream>>>(x0, sched, m, out, B);
    } else {
        ftp_kernel<<<B * 2, 256, 0, stream>>>(x0, x1, coeff, idx0, idx1, idx2, out);
    }
}

// Round 6
// 206.450 us; speedup vs baseline: 1.0162x; 1.0162x over previous
//
#include <hip/hip_runtime.h>

#define NUM_SEG 32
#define MUL 128
#define D 3
#define NUM_PATHS 64
#define ROW (NUM_SEG * MUL * D)   // 12288 floats per batch row
#define SEGF (MUL * D)            // 384 floats per full segment row
#define SEG_QF 96                 // floats per segment in a u-quarter (32 u * 3)

typedef float v2f __attribute__((ext_vector_type(2)));
typedef float v4f __attribute__((ext_vector_type(4)));

// ---------------------------------------------------------------------------
// Setup kernel (unchanged, proven): block 0 builds the compact schedule
// (segments sorted by path-count desc); blocks 1..B build m[b][p][3][3].
// ---------------------------------------------------------------------------
__global__ __launch_bounds__(64) void ftp_setup(
    const float* __restrict__ x1, const float* __restrict__ coeff,
    const int* __restrict__ idx0, const int* __restrict__ idx1,
    const int* __restrict__ idx2,
    unsigned int* __restrict__ sched, float* __restrict__ m)
{
    const int tid = threadIdx.x;
    if (blockIdx.x == 0) {
        __shared__ int lcnt[NUM_SEG];
        __shared__ int loff[NUM_SEG];
        __shared__ int lperm[NUM_SEG];
        __shared__ unsigned short lent[NUM_PATHS];
        if (tid < NUM_SEG) lcnt[tid] = 0;
        __syncthreads();
        const int p   = tid;
        const int s2  = idx2[p];
        const int pos = atomicAdd(&lcnt[s2], 1);
        __syncthreads();
        if (tid == 0) {
            int off = 0;
            for (int s = 0; s < NUM_SEG; ++s) { loff[s] = off; off += lcnt[s]; }
            int perm[NUM_SEG];
            for (int s = 0; s < NUM_SEG; ++s) perm[s] = s;
            for (int i = 1; i < NUM_SEG; ++i) {          // insertion sort, cnt desc
                int v = perm[i], cv = lcnt[v], j = i - 1;
                while (j >= 0 && lcnt[perm[j]] < cv) { perm[j + 1] = perm[j]; --j; }
                perm[j + 1] = v;
            }
            for (int s = 0; s < NUM_SEG; ++s) lperm[s] = perm[s];
        }
        __syncthreads();
        lent[loff[s2] + pos] = (unsigned short)(idx0[p] | (p << 8));
        __syncthreads();
        if (tid < NUM_SEG) {
            const int sg = lperm[tid];
            sched[tid] = (unsigned)lcnt[sg] | ((unsigned)loff[sg] << 8)
                       | ((unsigned)sg << 16);
        }
        if (tid < NUM_PATHS / 2) {
            sched[NUM_SEG + tid] = (unsigned)lent[2 * tid]
                                 | ((unsigned)lent[2 * tid + 1] << 16);
        }
    } else {
        const int b = blockIdx.x - 1;
        const int p = tid;
        const float* xr = x1 + (size_t)b * (NUM_SEG * D) + idx1[p] * D;
        const float j0 = xr[0], j1 = xr[1], j2 = xr[2];
        const float* cf = coeff + p * 27;
        float* mp = m + (size_t)b * (NUM_PATHS * 9) + p * 9;
        #pragma unroll
        for (int i = 0; i < D; ++i)
            #pragma unroll
            for (int k = 0; k < D; ++k)
                mp[i * 3 + k] = j0 * cf[i * 9 + k]
                              + j1 * cf[i * 9 + 3 + k]
                              + j2 * cf[i * 9 + 6 + k];
    }
}

// ---------------------------------------------------------------------------
// Main kernel: R4 structure (u-quarter blocks, 14.8 KB LDS, 8 blocks/CU)
// with ONE change: output stores are NON-TEMPORAL. out has zero reuse --
// caching it only evicts x0 from L2/L3. nt stores keep x0 LLC-resident.
// ---------------------------------------------------------------------------
__global__ __launch_bounds__(256) void ftp_main(
    const float* __restrict__ x0, const unsigned int* __restrict__ sched,
    const float* __restrict__ m, float* __restrict__ out)
{
    const int bid = blockIdx.x;
    const int b   = bid >> 2;          // batch row
    const int qt  = bid & 3;           // u-quarter: u in [32*qt, 32*qt+32)
    const int tid = threadIdx.x;

    __shared__ __align__(16) float s_x0[NUM_SEG * SEG_QF];   // 12288 B [seg][96]
    __shared__ __align__(16) float s_m[NUM_PATHS][9];        //  2304 B
    __shared__ unsigned int s_sched[NUM_SEG];                //   128 B
    __shared__ unsigned int s_entw[NUM_PATHS / 2];           //   128 B

    // ---- async stage u-quarter of x0 row: 3 x global_load_lds dwordx4 ----
    const v4f* __restrict__ srcb = (const v4f*)(x0 + (size_t)b * ROW);
    #pragma unroll
    for (int j = 0; j < 3; ++j) {
        const int F   = j * 256 + tid;       // f4 index in [0,768)
        const int seg = F / 24;              // const-div -> magic mul
        const int in4 = F - seg * 24;
        const v4f* gp = srcb + seg * 96 + qt * 24 + in4;
        __builtin_amdgcn_global_load_lds(
            (const __attribute__((address_space(1))) void*)gp,
            (__attribute__((address_space(3))) void*)((v4f*)s_x0 + F),
            16, 0, 0);
    }

    // ---- stage m (144 v4f) + schedule (64 words) ----
    if (tid < 144) {
        const v4f* mg = (const v4f*)(m + (size_t)b * (NUM_PATHS * 9));
        ((v4f*)s_m)[tid] = mg[tid];
    } else if (tid < 176) {
        s_sched[tid - 144] = sched[tid - 144];
    } else if (tid < 208) {
        s_entw[tid - 176] = sched[NUM_SEG + (tid - 176)];
    }
    __syncthreads();

    // ---- compute: thread owns (seg-slot ss, u-pair q); 2 slots, snake-paired ----
    const int q  = tid & 15;           // u-pair within quarter: local u = 2q, 2q+1
    const int ss = tid >> 4;           // 16 concurrent segment slots
    const unsigned short* s_ent = (const unsigned short*)s_entw;
    float* __restrict__ ob = out + (size_t)b * ROW + qt * SEG_QF + q * 6;

    #pragma unroll
    for (int si = 0; si < 2; ++si) {
        // snake pairing over count-sorted slots: ranks ss and 31-ss -> uniform sums
        const unsigned sc = s_sched[si ? (31 - ss) : ss];
        const int n   = sc & 255;
        const int off = (sc >> 8) & 255;
        const int s   = sc >> 16;
        float a00 = 0, a01 = 0, a02 = 0, a10 = 0, a11 = 0, a12 = 0;
        for (int t = 0; t < n; ++t) {
            const int e = s_ent[off + t];        // seg0 | p<<8 (16-lane uniform)
            const float* xs = s_x0 + (e & 255) * SEG_QF + q * 6;
            const float u00 = xs[0], u01 = xs[1], u02 = xs[2];
            const float u10 = xs[3], u11 = xs[4], u12 = xs[5];
            const float* mm = s_m[e >> 8];       // broadcast
            a00 += u00 * mm[0] + u01 * mm[3] + u02 * mm[6];
            a01 += u00 * mm[1] + u01 * mm[4] + u02 * mm[7];
            a02 += u00 * mm[2] + u01 * mm[5] + u02 * mm[8];
            a10 += u10 * mm[0] + u11 * mm[3] + u12 * mm[6];
            a11 += u10 * mm[1] + u11 * mm[4] + u12 * mm[7];
            a12 += u10 * mm[2] + u11 * mm[5] + u12 * mm[8];
        }
        float* o = ob + s * SEGF;                // 16 lanes -> 384B contiguous
        v2f O0 = {a00, a01}, O1 = {a02, a10}, O2 = {a11, a12};
        __builtin_nontemporal_store(O0, (v2f*)(o + 0));
        __builtin_nontemporal_store(O1, (v2f*)(o + 2));
        __builtin_nontemporal_store(O2, (v2f*)(o + 4));
    }
}

// ---------------------------------------------------------------------------
// Fallback: original verified kernel (used only if ws_size is too small).
// ---------------------------------------------------------------------------
#define HALF_F4 1536
#define SEG_HF 192

__global__ __launch_bounds__(256) void ftp_kernel(
    const float* __restrict__ x0, const float* __restrict__ x1,
    const float* __restrict__ coeff, const int* __restrict__ idx0,
    const int* __restrict__ idx1, const int* __restrict__ idx2,
    float* __restrict__ out)
{
    const int bid = blockIdx.x;
    const int b   = bid >> 1;
    const int h   = bid & 1;
    const int tid = threadIdx.x;

    __shared__ v4f   s_x0[HALF_F4];
    __shared__ float s_m[NUM_PATHS][9];
    __shared__ unsigned short s_pe[NUM_SEG][NUM_PATHS];
    __shared__ int   s_cnt[NUM_SEG];

    if (tid < NUM_SEG) s_cnt[tid] = 0;
    __syncthreads();

    const v4f* __restrict__ src = (const v4f*)(x0 + (size_t)b * ROW);
    #pragma unroll
    for (int j = 0; j < 6; ++j) {
        const int f     = j * 256 + tid;
        const int seg   = f / 48;
        const int inner = f - seg * 48;
        s_x0[f] = src[seg * 96 + h * 48 + inner];
    }

    if (tid < NUM_PATHS) {
        const int p  = tid;
        const int s0 = idx0[p];
        const int i1 = idx1[p];
        const int s2 = idx2[p];
        const int pos = atomicAdd(&s_cnt[s2], 1);
        s_pe[s2][pos] = (unsigned short)(s0 | (p << 8));

        const float* xr = x1 + (size_t)b * (NUM_SEG * D) + i1 * D;
        const float j0 = xr[0], j1 = xr[1], j2 = xr[2];
        const float* cf = coeff + p * 27;
        #pragma unroll
        for (int i = 0; i < D; ++i)
            #pragma unroll
            for (int k = 0; k < D; ++k)
                s_m[p][i * 3 + k] = j0 * cf[i * 9 + k]
                                  + j1 * cf[i * 9 + 3 + k]
                                  + j2 * cf[i * 9 + 6 + k];
    }
    __syncthreads();

    const int q  = tid & 31;
    const int ss = tid >> 5;
    float* __restrict__ ob = out + (size_t)b * ROW + h * SEG_HF + q * 6;
    const float* __restrict__ sx = (const float*)s_x0;

    #pragma unroll
    for (int si = 0; si < 4; ++si) {
        const int s = ss + si * 8;
        float a00 = 0, a01 = 0, a02 = 0, a10 = 0, a11 = 0, a12 = 0;
        const int n = s_cnt[s];
        for (int t = 0; t < n; ++t) {
            const int e = s_pe[s][t];
            const float* xs = sx + (e & 255) * SEG_HF + q * 6;
            const float u00 = xs[0], u01 = xs[1], u02 = xs[2];
            const float u10 = xs[3], u11 = xs[4], u12 = xs[5];
            const float* mm = s_m[e >> 8];
            a00 += u00 * mm[0] + u01 * mm[3] + u02 * mm[6];
            a01 += u00 * mm[1] + u01 * mm[4] + u02 * mm[7];
            a02 += u00 * mm[2] + u01 * mm[5] + u02 * mm[8];
            a10 += u10 * mm[0] + u11 * mm[3] + u12 * mm[6];
            a11 += u10 * mm[1] + u11 * mm[4] + u12 * mm[7];
            a12 += u10 * mm[2] + u11 * mm[5] + u12 * mm[8];
        }
        float* o = ob + s * SEGF;
        v2f O0 = {a00, a01}, O1 = {a02, a10}, O2 = {a11, a12};
        *(v2f*)(o + 0) = O0;
        *(v2f*)(o + 2) = O1;
        *(v2f*)(o + 4) = O2;
    }
}

extern "C" void kernel_launch(void* const* d_in, const int* in_sizes, int n_in,
                              void* d_out, int out_size, void* d_ws, size_t ws_size,
                              hipStream_t stream) {
    const float* x0    = (const float*)d_in[0];
    const float* x1    = (const float*)d_in[1];
    const float* coeff = (const float*)d_in[2];
    const int*   idx0  = (const int*)d_in[3];
    const int*   idx1  = (const int*)d_in[4];
    const int*   idx2  = (const int*)d_in[5];
    float* out = (float*)d_out;

    const int B = in_sizes[0] / ROW;

    const size_t schedBytes = (size_t)(NUM_SEG + NUM_PATHS / 2) * sizeof(unsigned int);
    const size_t schedPad   = (schedBytes + 255) & ~(size_t)255;   // 256B-align m
    const size_t mBytes     = (size_t)B * NUM_PATHS * 9 * sizeof(float);

    if (ws_size >= schedPad + mBytes) {
        unsigned int* sched = (unsigned int*)d_ws;
        float*        m     = (float*)((char*)d_ws + schedPad);
        ftp_setup<<<B + 1, 64, 0, stream>>>(x1, coeff, idx0, idx1, idx2, sched, m);
        ftp_main<<<B * 4, 256, 0, stream>>>(x0, sched, m, out);
    } else {
        ftp_kernel<<<B * 2, 256, 0, stream>>>(x0, x1, coeff, idx0, idx1, idx2, out);
    }
}